// Round 5
// baseline (592.225 us; speedup 1.0000x reference)
//
#include <hip/hip_runtime.h>
#include <hip/hip_bf16.h>

// B=8, R=8, N=1024, D_IN=D_OUT=256, all fp32 in/out.
// prep_w : Wt[r][e][d] = bf16(W[r][d][e])          (scratch: first 1 MB of d_out)
// stage 1: sup[b,r,e,n] = bf16(x@W + bias)          (ws[0:32MB])
// stage 2: part[r][b][m][e] = adj[b,r,m,:]@sup[b,r,:,e]  (split-K=8 over r, plain stores)
// stage 3: out = relu(sum_r part[r]) fused reduce.
//
// R9: atomics->plain stores+reduce: gemm 167->~150us. Real but small.
// R10: five rounds of in-block schedule surgery (dbuf, counted vmcnt, DMA swizzle) were ALL
// neutral -> the barrier-synced 4-wave block structure itself is the constraint: waves are
// barrier-coupled every K-step, 2-3 blocks/CU, counters show everything idle (Mfma 8%,
// VALU 9%, HBM 16%, Occ 27-40%) while LDS tiles buy only 2x reuse on streaming operands.
// Rewrote both GEMMs as BARRIER-FREE, LDS-FREE, 1-wave (64-thread) blocks: MFMA fragments
// loaded directly from global (fp32 operands: load8+f2bf; bf16 operands: one short8),
// fragment addressing transcribed 1:1 from the proven LDS reads. Occupancy now VGPR-bound
// (~16 waves/CU of independent work); latency hidden by TLP, not choreography.
// L2 plan: gemm bid&7 = r -> all m/e tiles of one relation on one XCD (adj streamed once,
// sup[b,r] 512KB L2-resident); support bid&7 = b -> x[b] 4MB L2-resident per XCD.

#define Rr 8
#define Nn 1024
#define Dd 256

typedef __attribute__((ext_vector_type(8))) short short8;
typedef __attribute__((ext_vector_type(4))) float f32x4;

__device__ __forceinline__ short f2bf(float f) {
    unsigned u = __builtin_bit_cast(unsigned, f);
    u += 0x7fffu + ((u >> 16) & 1u);   // RNE
    return (short)(u >> 16);
}

__device__ __forceinline__ short8 cvt8(f32x4 lo, f32x4 hi) {
    short8 t;
    t[0] = f2bf(lo[0]); t[1] = f2bf(lo[1]); t[2] = f2bf(lo[2]); t[3] = f2bf(lo[3]);
    t[4] = f2bf(hi[0]); t[5] = f2bf(hi[1]); t[6] = f2bf(hi[2]); t[7] = f2bf(hi[3]);
    return t;
}

// ---------------- prep: Wt[r][e][d] bf16 <- W[r][d][e] f32 ----------------
__global__ void prep_w_kernel(const float* __restrict__ W, short* __restrict__ Wt) {
    __shared__ short T[64][72];
    const int tid = threadIdx.x;
    const int et = blockIdx.x, dt = blockIdx.y, r = blockIdx.z;
    const float* Wr = W + ((size_t)r * Dd + dt * 64) * Dd + et * 64;
    #pragma unroll
    for (int i = 0; i < 4; ++i) {
        int idx = tid + i * 256;
        int d_l = idx >> 4;
        int e4  = (idx & 15) * 4;
        f32x4 v = *(const f32x4*)(Wr + d_l * Dd + e4);
        T[e4 + 0][d_l] = f2bf(v[0]);
        T[e4 + 1][d_l] = f2bf(v[1]);
        T[e4 + 2][d_l] = f2bf(v[2]);
        T[e4 + 3][d_l] = f2bf(v[3]);
    }
    __syncthreads();
    short* o = Wt + ((size_t)r * Dd + et * 64) * Dd + dt * 64;
    #pragma unroll
    for (int i = 0; i < 2; ++i) {
        int idx = tid + i * 256;
        *(short8*)(o + (idx >> 3) * Dd + (idx & 7) * 8) = *(const short8*)&T[idx >> 3][(idx & 7) * 8];
    }
}

// ---------------- Stage 1: sup[b,r,e,n] = bf16(Wt @ x^T + bias) ----------------
// 1 wave per block, 64e x 64n tile, K=256 (8 k-steps of 32).
// bid = b + 8*(e_t + 4*(n_t + 16*r)) -> bid&7 = b: all tiles of batch b share an XCD
// (x[b] 4MB L2-resident); 4 e_t x 16 n_t x 8 r x 8 b = 4096 blocks.
__global__ __launch_bounds__(64, 3) void support_kernel(
        const float* __restrict__ x, const short* __restrict__ Wt,
        const float* __restrict__ bias, short* __restrict__ sup) {
    const int lane = threadIdx.x;
    const int quad = lane >> 4, l16 = lane & 15;
    const int bid = blockIdx.x;
    const int b   = bid & 7;
    const int e_t = (bid >> 3) & 3;
    const int n_t = (bid >> 5) & 15;
    const int r   = bid >> 9;

    const short* wp = Wt + ((size_t)r * Dd + e_t * 64) * Dd;
    const float* xb = x + ((size_t)b * Nn + n_t * 64) * Dd;

    f32x4 acc[4][4] = {};
    #pragma unroll 2
    for (int kt = 0; kt < 8; ++kt) {
        const int d0 = kt * 32;
        short8 a[4], bfr[4];
        #pragma unroll
        for (int i = 0; i < 4; ++i)
            a[i] = *(const short8*)(wp + (i * 16 + l16) * Dd + d0 + quad * 8);
        #pragma unroll
        for (int j = 0; j < 4; ++j) {
            const float* p = xb + (j * 16 + l16) * Dd + d0 + quad * 8;
            bfr[j] = cvt8(*(const f32x4*)p, *(const f32x4*)(p + 4));
        }
        #pragma unroll
        for (int i = 0; i < 4; ++i)
            #pragma unroll
            for (int j = 0; j < 4; ++j)
                acc[i][j] = __builtin_amdgcn_mfma_f32_16x16x32_bf16(a[i], bfr[j], acc[i][j], 0, 0, 0);
    }

    // Epilogue: C[row=e][col=n]; add bias; bf16 store to sup[(b,r),e,n].
    #pragma unroll
    for (int i = 0; i < 4; ++i)
        #pragma unroll
        for (int reg = 0; reg < 4; ++reg) {
            int e = e_t * 64 + i * 16 + quad * 4 + reg;
            float bv = bias[r * Dd + e];
            #pragma unroll
            for (int j = 0; j < 4; ++j) {
                int n = n_t * 64 + j * 16 + l16;
                sup[(((b * Rr + r) * Dd + e) << 10) + n] = f2bf(acc[i][j][reg] + bv);
            }
        }
}

// ---------------- Stage 2: part[r][b][m][e] = adj @ sup^T (1 wave/block) ----------------
// 32m x 64e tile per wave, K=1024 (32 k-steps of 32), split-K over r.
// bid = r + 8*(e_t + 4*(m_t + 32*b)) -> bid&7 = r: all tiles of relation r share an XCD
// (adj[b][r] streamed once, sup[b][r] 512KB L2-resident); 4 e_t x 32 m_t x 8 b x 8 r = 8192.
__global__ __launch_bounds__(64, 4) void gcn_gemm_kernel(
        const float* __restrict__ adj, const short* __restrict__ sup,
        float* __restrict__ part) {
    const int lane = threadIdx.x;
    const int quad = lane >> 4, l16 = lane & 15;
    const int bid = blockIdx.x;
    const int r   = bid & 7;
    const int e_t = (bid >> 3) & 3;
    const int m_t = (bid >> 5) & 31;
    const int b   = bid >> 10;

    const float* ap = adj + ((size_t)((b * Rr + r) * Nn + m_t * 32)) * Nn;
    const short* bp = sup + (((size_t)((b * Rr + r) * Dd + e_t * 64)) << 10);

    f32x4 acc[2][4] = {};
    #pragma unroll 2
    for (int kt = 0; kt < 32; ++kt) {
        const int k0 = kt * 32;
        short8 a[2], bfr[4];
        #pragma unroll
        for (int i = 0; i < 2; ++i) {
            const float* p = ap + (size_t)(i * 16 + l16) * Nn + k0 + quad * 8;
            a[i] = cvt8(*(const f32x4*)p, *(const f32x4*)(p + 4));
        }
        #pragma unroll
        for (int j = 0; j < 4; ++j)
            bfr[j] = *(const short8*)(bp + ((size_t)(j * 16 + l16) << 10) + k0 + quad * 8);
        #pragma unroll
        for (int i = 0; i < 2; ++i)
            #pragma unroll
            for (int j = 0; j < 4; ++j)
                acc[i][j] = __builtin_amdgcn_mfma_f32_16x16x32_bf16(a[i], bfr[j], acc[i][j], 0, 0, 0);
    }

    // Epilogue: C[row=m][col=e]; plain fp32 stores to this relation's partial slab.
    float* pr = part + ((size_t)r << 21) + ((size_t)b * Nn + m_t * 32) * Dd + e_t * 64;
    #pragma unroll
    for (int i = 0; i < 2; ++i)
        #pragma unroll
        for (int reg = 0; reg < 4; ++reg) {
            int m_l = i * 16 + quad * 4 + reg;
            #pragma unroll
            for (int j = 0; j < 4; ++j)
                pr[(size_t)m_l * Dd + j * 16 + l16] = acc[i][j][reg];
        }
}

// ---------------- Stage 3: out = relu(sum_r part[r]) ----------------
__global__ __launch_bounds__(256) void reduce_relu_kernel(
        const float* __restrict__ part, float* __restrict__ out, int n4) {
    int i = blockIdx.x * blockDim.x + threadIdx.x;
    if (i >= n4) return;
    const f32x4* p = (const f32x4*)part;
    f32x4 v = p[i];
    #pragma unroll
    for (int k = 1; k < 8; ++k) {
        f32x4 t = p[i + ((size_t)k << 19)];   // slab stride = 2M floats = 512K f32x4
        v[0] += t[0]; v[1] += t[1]; v[2] += t[2]; v[3] += t[3];
    }
    v[0] = fmaxf(v[0], 0.f); v[1] = fmaxf(v[1], 0.f);
    v[2] = fmaxf(v[2], 0.f); v[3] = fmaxf(v[3], 0.f);
    ((f32x4*)out)[i] = v;
}

extern "C" void kernel_launch(void* const* d_in, const int* in_sizes, int n_in,
                              void* d_out, int out_size, void* d_ws, size_t ws_size,
                              hipStream_t stream) {
    const float* x    = (const float*)d_in[0];
    const float* adj  = (const float*)d_in[1];
    const float* W    = (const float*)d_in[2];
    const float* bias = (const float*)d_in[3];
    float* out = (float*)d_out;
    short* sup  = (short*)d_ws;                              // ws[0:32MB)
    float* part = (float*)((char*)d_ws + (32u << 20));       // ws[32MB:96MB), [r][b][m][e] fp32
    short* Wt   = (short*)d_out;   // 1 MB scratch inside d_out, overwritten by reduce at the end

    prep_w_kernel<<<dim3(4, 4, 8), 256, 0, stream>>>(W, Wt);
    support_kernel<<<4096, 64, 0, stream>>>(x, Wt, bias, sup);
    gcn_gemm_kernel<<<8192, 64, 0, stream>>>(adj, sup, part);
    reduce_relu_kernel<<<(out_size / 4 + 255) / 256, 256, 0, stream>>>(part, out, out_size / 4);
}

// Round 6
// 450.031 us; speedup vs baseline: 1.3160x; 1.3160x over previous
//
#include <hip/hip_runtime.h>
#include <hip/hip_bf16.h>

// B=8, R=8, N=1024, D_IN=D_OUT=256, all fp32 in/out.
// prep_w : Wt[r][e][d] = bf16(W[r][d][e])      (ws[32MB:36MB))
// stage 1: sup[b,r,e,n] = bf16(x@W + bias)      (ws[0:32MB))
// stage 2: out[b,m,e] = relu(sum_r adj[b,r,m,:] @ sup[b,r,:,e])  -- FUSED over r, no split-K.
//
// R11: R2(4-wave LDS)=167us, R4(no atomics)=150us, R5(1-wave no-LDS, 49% occ)=262us -- all
// latency-bound with every pipe idle. The invariant was TRANSACTION DENSITY: every global
// load pattern was scattered small segments (worst: 64 lanes x 16B at 2KB stride = 64
// partial lines/inst; adj: 16 rows x 128B). ~100-250 line-requests per wave-iter floods the
// CU's memory path -> latency-under-load 3-10K cyc/iter. (The harness fill kernel hits 6.6
// TB/s at 10% occupancy with dense 1KB/inst access -- density, not occupancy, is the lever.)
// Rebuilt: tiles are [64 rows x 256 K], lanes cover WHOLE contiguous rows (2 rows/inst,
// dense lines); MFMA fragment redistribution via pitch-264 LDS (bank-uniform at b128 data
// limit). r-loop fused into gemm K-loop (K=8192, 32 stages): fp32 acc in regs, ReLU fused,
// part slab + reduce + memset deleted. Epilogues densified via LDS bounce. XCD: bid%8=b ->
// adj fetched once/XCD (256MB total), sup L2-shared across m-tiles (32MB).

#define Rr 8
#define Nn 1024
#define Dd 256
#define AP 264   // staging pitch (shorts) for 256-wide bf16 rows: row stride 528B -> banks +4/row
#define EPF 68   // gemm epilogue f32 pitch (dwords)
#define EPS 72   // support epilogue bf16 pitch (shorts), 144B rows (16B-aligned)

typedef __attribute__((ext_vector_type(8))) short short8;
typedef __attribute__((ext_vector_type(4))) float f32x4;

__device__ __forceinline__ short f2bf(float f) {
    unsigned u = __builtin_bit_cast(unsigned, f);
    u += 0x7fffu + ((u >> 16) & 1u);   // RNE
    return (short)(u >> 16);
}

__device__ __forceinline__ short8 cvt8(f32x4 lo, f32x4 hi) {
    short8 t;
    t[0] = f2bf(lo[0]); t[1] = f2bf(lo[1]); t[2] = f2bf(lo[2]); t[3] = f2bf(lo[3]);
    t[4] = f2bf(hi[0]); t[5] = f2bf(hi[1]); t[6] = f2bf(hi[2]); t[7] = f2bf(hi[3]);
    return t;
}

// ---------------- prep: Wt[r][e][d] bf16 <- W[r][d][e] f32 ----------------
__global__ void prep_w_kernel(const float* __restrict__ W, short* __restrict__ Wt) {
    __shared__ short T[64][72];
    const int tid = threadIdx.x;
    const int et = blockIdx.x, dt = blockIdx.y, r = blockIdx.z;
    const float* Wr = W + ((size_t)r * Dd + dt * 64) * Dd + et * 64;
    #pragma unroll
    for (int i = 0; i < 4; ++i) {
        int idx = tid + i * 256;
        int d_l = idx >> 4;
        int e4  = (idx & 15) * 4;
        f32x4 v = *(const f32x4*)(Wr + d_l * Dd + e4);
        T[e4 + 0][d_l] = f2bf(v[0]);
        T[e4 + 1][d_l] = f2bf(v[1]);
        T[e4 + 2][d_l] = f2bf(v[2]);
        T[e4 + 3][d_l] = f2bf(v[3]);
    }
    __syncthreads();
    short* o = Wt + ((size_t)r * Dd + et * 64) * Dd + dt * 64;
    #pragma unroll
    for (int i = 0; i < 2; ++i) {
        int idx = tid + i * 256;
        *(short8*)(o + (idx >> 3) * Dd + (idx & 7) * 8) = *(const short8*)&T[idx >> 3][(idx & 7) * 8];
    }
}

// ---------------- Stage 1: sup[b,r,e,n] = bf16(Wt @ x^T + bias) ----------------
// block 256 (4 waves, 2e x 2n), tile 64e x 64n, K=256 single stage.
// bid = b + 8*(e_t + 4*(n_t + 16*r)); bid%8=b -> x[b] (4MB eff) L2-resident per XCD.
__global__ __launch_bounds__(256, 2) void support_kernel(
        const float* __restrict__ x, const short* __restrict__ Wt,
        const float* __restrict__ bias, short* __restrict__ sup) {
    __shared__ short As[64 * AP];   // Wt rows  [e][d]
    __shared__ short Bs[64 * AP];   // x rows   [n][d] (cvt bf16)

    const int tid = threadIdx.x;
    const int wave = tid >> 6, lane = tid & 63;
    const int quad = lane >> 4, l16 = lane & 15;
    const int bid = blockIdx.x;
    const int b   = bid & 7;
    const int e_t = (bid >> 3) & 3;
    const int n_t = (bid >> 5) & 15;
    const int r   = bid >> 9;
    const int e0 = e_t * 64, n0 = n_t * 64;
    const int we = wave & 1, wn = wave >> 1;

    const short* wp = Wt + ((size_t)r * Dd + e0) * Dd;
    const float* xb = x + ((size_t)b * Nn + n0) * Dd;

    // stage Wt: 64 rows x 512B; lanes cover whole rows (2 rows/inst, dense).
    #pragma unroll
    for (int p = 0; p < 8; ++p) {
        int idx = tid + p * 256;
        int row = idx >> 5, c = idx & 31;
        *(short8*)&As[row * AP + c * 8] = *(const short8*)(wp + row * Dd + c * 8);
    }
    // stage x: 64 rows x 1KB fp32 -> bf16; 32B/lane pairs, dense rows.
    #pragma unroll
    for (int p = 0; p < 8; ++p) {
        int idx = tid + p * 256;
        int row = idx >> 5, c = idx & 31;
        const float* pp = xb + row * Dd + c * 8;
        *(short8*)&Bs[row * AP + c * 8] = cvt8(*(const f32x4*)pp, *(const f32x4*)(pp + 4));
    }
    __syncthreads();

    f32x4 acc[2][2] = {};
    #pragma unroll
    for (int kk = 0; kk < 8; ++kk) {
        short8 a[2], bb[2];
        #pragma unroll
        for (int i = 0; i < 2; ++i)
            a[i] = *(const short8*)&As[(we * 32 + i * 16 + l16) * AP + kk * 32 + quad * 8];
        #pragma unroll
        for (int j = 0; j < 2; ++j)
            bb[j] = *(const short8*)&Bs[(wn * 32 + j * 16 + l16) * AP + kk * 32 + quad * 8];
        #pragma unroll
        for (int i = 0; i < 2; ++i)
            #pragma unroll
            for (int j = 0; j < 2; ++j)
                acc[i][j] = __builtin_amdgcn_mfma_f32_16x16x32_bf16(a[i], bb[j], acc[i][j], 0, 0, 0);
    }

    // epilogue: bias + bf16 via LDS bounce, then dense row stores.
    __syncthreads();
    short* E = As;   // reuse; 64 x EPS(72) shorts = 9216B
    #pragma unroll
    for (int i = 0; i < 2; ++i)
        #pragma unroll
        for (int reg = 0; reg < 4; ++reg) {
            int row = we * 32 + i * 16 + quad * 4 + reg;
            float bv = bias[r * Dd + e0 + row];
            #pragma unroll
            for (int j = 0; j < 2; ++j)
                E[row * EPS + wn * 32 + j * 16 + l16] = f2bf(acc[i][j][reg] + bv);
        }
    __syncthreads();
    #pragma unroll
    for (int p = 0; p < 2; ++p) {
        int idx = tid + p * 256;
        int row = idx >> 3, c = idx & 7;
        *(short8*)(sup + (((size_t)((b * Rr + r) * Dd + e0 + row)) << 10) + n0 + c * 8) =
            *(const short8*)&E[row * EPS + c * 8];
    }
}

// ---------------- Stage 2: out = relu(sum_r adj @ sup^T), fused over r ----------------
// block 256 (4 waves, 2m x 2e), tile 64m x 64e, K = 8*1024, 32 stages of 256.
// bid = b + 8*(e_t + 4*m_t); bid%8=b -> one batch per XCD: adj streamed once, sup L2-shared.
__global__ __launch_bounds__(256, 2) void gcn_gemm_kernel(
        const float* __restrict__ adj, const short* __restrict__ sup,
        float* __restrict__ out) {
    __shared__ short As[64 * AP];   // adj rows [m][k] (cvt bf16)
    __shared__ short Bs[64 * AP];   // sup rows [e][k]

    const int tid = threadIdx.x;
    const int wave = tid >> 6, lane = tid & 63;
    const int quad = lane >> 4, l16 = lane & 15;
    const int bid = blockIdx.x;
    const int b   = bid & 7;
    const int e_t = (bid >> 3) & 3;
    const int m_t = bid >> 5;
    const int e0 = e_t * 64, m0 = m_t * 64;
    const int wm = wave & 1, we = wave >> 1;

    f32x4 axv[16];   // adj stage regs: 8 pairs
    short8 sv[8];    // sup stage regs

    auto gload = [&](int rr, int ks) {
        const float* ap = adj + ((size_t)(b * Rr + rr) * Nn + m0) * Nn + ks;
        const short* bp = sup + (((size_t)((b * Rr + rr) * Dd + e0)) << 10) + ks;
        #pragma unroll
        for (int p = 0; p < 8; ++p) {
            int idx = tid + p * 256;
            int row = idx >> 5, c = idx & 31;
            const float* pp = ap + (size_t)row * Nn + c * 8;
            axv[2 * p]     = *(const f32x4*)pp;
            axv[2 * p + 1] = *(const f32x4*)(pp + 4);
            sv[p] = *(const short8*)(bp + ((size_t)row << 10) + c * 8);
        }
    };
    auto stage = [&]() {
        #pragma unroll
        for (int p = 0; p < 8; ++p) {
            int idx = tid + p * 256;
            int row = idx >> 5, c = idx & 31;
            *(short8*)&As[row * AP + c * 8] = cvt8(axv[2 * p], axv[2 * p + 1]);
            *(short8*)&Bs[row * AP + c * 8] = sv[p];
        }
    };

    f32x4 acc[2][2] = {};
    gload(0, 0);
    for (int st = 0; st < 32; ++st) {
        stage();
        __syncthreads();
        if (st < 31) gload((st + 1) >> 2, ((st + 1) & 3) * 256);   // flies over compute
        #pragma unroll
        for (int kk = 0; kk < 8; ++kk) {
            short8 a[2], bb[2];
            #pragma unroll
            for (int i = 0; i < 2; ++i)
                a[i] = *(const short8*)&As[(wm * 32 + i * 16 + l16) * AP + kk * 32 + quad * 8];
            #pragma unroll
            for (int j = 0; j < 2; ++j)
                bb[j] = *(const short8*)&Bs[(we * 32 + j * 16 + l16) * AP + kk * 32 + quad * 8];
            #pragma unroll
            for (int i = 0; i < 2; ++i)
                #pragma unroll
                for (int j = 0; j < 2; ++j)
                    acc[i][j] = __builtin_amdgcn_mfma_f32_16x16x32_bf16(a[i], bb[j], acc[i][j], 0, 0, 0);
        }
        __syncthreads();
    }

    // epilogue: ReLU via f32 LDS bounce, then dense 256B row stores.
    float* E = (float*)As;   // 64 x EPF(68) dwords = 17408B (fits in As)
    #pragma unroll
    for (int i = 0; i < 2; ++i)
        #pragma unroll
        for (int reg = 0; reg < 4; ++reg) {
            int row = wm * 32 + i * 16 + quad * 4 + reg;
            #pragma unroll
            for (int j = 0; j < 2; ++j)
                E[row * EPF + we * 32 + j * 16 + l16] = fmaxf(acc[i][j][reg], 0.f);
        }
    __syncthreads();
    #pragma unroll
    for (int p = 0; p < 4; ++p) {
        int idx = tid + p * 256;
        int row = idx >> 4, c = idx & 15;
        *(f32x4*)(out + ((size_t)(b * Nn + m0 + row)) * Dd + e0 + c * 4) =
            *(const f32x4*)&E[row * EPF + c * 4];
    }
}

extern "C" void kernel_launch(void* const* d_in, const int* in_sizes, int n_in,
                              void* d_out, int out_size, void* d_ws, size_t ws_size,
                              hipStream_t stream) {
    const float* x    = (const float*)d_in[0];
    const float* adj  = (const float*)d_in[1];
    const float* W    = (const float*)d_in[2];
    const float* bias = (const float*)d_in[3];
    float* out = (float*)d_out;
    short* sup = (short*)d_ws;                          // ws[0:32MB)
    short* Wt  = (short*)((char*)d_ws + (32u << 20));   // ws[32MB:36MB)

    prep_w_kernel<<<dim3(4, 4, 8), 256, 0, stream>>>(W, Wt);
    support_kernel<<<4096, 256, 0, stream>>>(x, Wt, bias, sup);
    gcn_gemm_kernel<<<512, 256, 0, stream>>>(adj, sup, out);
}

// Round 7
// 442.279 us; speedup vs baseline: 1.3390x; 1.0175x over previous
//
#include <hip/hip_runtime.h>

// B=8, R=8, N=1024, D_IN=D_OUT=256, all fp32 in/out.
// prep_w : Wt[r][e][d] = bf16(W[r][d][e])      (ws[32MB:36MB))
// stage 1: sup[b,r,e,n] = bf16(x@W + bias)      (ws[0:32MB))
// stage 2: out[b,m,e] = relu(sum_r adj[b,r,m,:] @ sup[b,r,:,e])  fused over r.
//
// R12: R3 = counted-vmcnt depth + SCATTERED loads = 167us; R6 = DENSE loads + __syncthreads
// (drains vmcnt(0) every stage, killing the prefetch) = 161us. Each round fixed one of the
// two latency pathologies and was annulled by the other. This round combines them:
// both GEMMs on one skeleton -- 64x64 tile, K-slice 64, double-buffered LDS pitch 104
// (52 dw = 20 mod 32: proven conflict-free frag-read class), ONE raw s_barrier per stage,
// counted s_waitcnt vmcnt(6) (6 VMEM/stage, 2 stages in flight, issue->consume = 3 stages),
// dense 256B-row loads, 52KB LDS -> 3 blocks/CU. gemm: r fused into K (128 stages), ReLU
// fused, bijective XCD swizzle (XCD k owns 16 contiguous m-tiles of batch k>>1: adj
// streamed once/XCD, sup[b]=4MB L2-resident). support: same skeleton, 4 stages.

#define Rr 8
#define Nn 1024
#define Dd 256
#define SP 104   // LDS pitch (shorts) for 64-wide K-slices: 52 dwords = 20 mod 32
#define EPF 68   // gemm epilogue f32 bounce pitch
#define EPS 72   // support epilogue bf16 bounce pitch

typedef __attribute__((ext_vector_type(8))) short short8;
typedef __attribute__((ext_vector_type(4))) float f32x4;

__device__ __forceinline__ short f2bf(float f) {
    unsigned u = __builtin_bit_cast(unsigned, f);
    u += 0x7fffu + ((u >> 16) & 1u);   // RNE
    return (short)(u >> 16);
}

__device__ __forceinline__ short8 cvt8(f32x4 lo, f32x4 hi) {
    short8 t;
    t[0] = f2bf(lo[0]); t[1] = f2bf(lo[1]); t[2] = f2bf(lo[2]); t[3] = f2bf(lo[3]);
    t[4] = f2bf(hi[0]); t[5] = f2bf(hi[1]); t[6] = f2bf(hi[2]); t[7] = f2bf(hi[3]);
    return t;
}

// ---------------- prep: Wt[r][e][d] bf16 <- W[r][d][e] f32 ----------------
__global__ void prep_w_kernel(const float* __restrict__ W, short* __restrict__ Wt) {
    __shared__ short T[64][72];
    const int tid = threadIdx.x;
    const int et = blockIdx.x, dt = blockIdx.y, r = blockIdx.z;
    const float* Wr = W + ((size_t)r * Dd + dt * 64) * Dd + et * 64;
    #pragma unroll
    for (int i = 0; i < 4; ++i) {
        int idx = tid + i * 256;
        int d_l = idx >> 4;
        int e4  = (idx & 15) * 4;
        f32x4 v = *(const f32x4*)(Wr + d_l * Dd + e4);
        T[e4 + 0][d_l] = f2bf(v[0]);
        T[e4 + 1][d_l] = f2bf(v[1]);
        T[e4 + 2][d_l] = f2bf(v[2]);
        T[e4 + 3][d_l] = f2bf(v[3]);
    }
    __syncthreads();
    short* o = Wt + ((size_t)r * Dd + et * 64) * Dd + dt * 64;
    #pragma unroll
    for (int i = 0; i < 2; ++i) {
        int idx = tid + i * 256;
        *(short8*)(o + (idx >> 3) * Dd + (idx & 7) * 8) = *(const short8*)&T[idx >> 3][(idx & 7) * 8];
    }
}

// ---------------- Stage 1: sup[b,r,e,n] = bf16(Wt @ x^T + bias) ----------------
// 64e x 64n tile, K=256 in 4 stages of 64. grid 4096: d&7=b -> x[b] XCD-local.
__global__ __launch_bounds__(256, 3) void support_kernel(
        const float* __restrict__ x, const short* __restrict__ Wt,
        const float* __restrict__ bias, short* __restrict__ sup) {
    __shared__ short As[2][64 * SP];   // Wt rows [e][k]
    __shared__ short Bs[2][64 * SP];   // x  rows [n][k] (cvt bf16)

    const int tid = threadIdx.x;
    const int wave = tid >> 6, lane = tid & 63;
    const int quad = lane >> 4, l16 = lane & 15;
    const int lrow = tid >> 3, lc = tid & 7;
    const int d = blockIdx.x;
    const int b = d & 7, rest = d >> 3;
    const int e_t = rest & 3, n_t = (rest >> 2) & 15, r = rest >> 6;
    const int e0 = e_t * 64, n0 = n_t * 64;
    const int we = wave & 1, wn = wave >> 1;

    const short* wp = Wt + ((size_t)r * Dd + e0) * Dd;
    const float* xb = x + ((size_t)b * Nn + n0) * Dd;

    short8 Wa0[2], Wa1[2];
    f32x4  Xv0[4], Xv1[4];

#define SGLOAD(WW, XX, t) do { int d0_ = (t) * 64;                              \
        _Pragma("unroll")                                                       \
        for (int p_ = 0; p_ < 2; ++p_) { int row_ = lrow + p_ * 32;             \
            WW[p_] = *(const short8*)(wp + (size_t)row_ * Dd + d0_ + lc * 8);   \
            const float* px_ = xb + (size_t)row_ * Dd + d0_ + lc * 8;           \
            XX[2 * p_]     = *(const f32x4*)px_;                                \
            XX[2 * p_ + 1] = *(const f32x4*)(px_ + 4); } } while (0)

#define SWRITE(BW, WW, XX) do {                                                 \
        _Pragma("unroll")                                                       \
        for (int p_ = 0; p_ < 2; ++p_) { int row_ = lrow + p_ * 32;             \
            *(short8*)&As[BW][row_ * SP + lc * 8] = WW[p_];                     \
            *(short8*)&Bs[BW][row_ * SP + lc * 8] = cvt8(XX[2 * p_], XX[2 * p_ + 1]); } } while (0)

#define SCOMP(BR) do {                                                          \
        _Pragma("unroll")                                                       \
        for (int kk_ = 0; kk_ < 2; ++kk_) { short8 af_[2], bf_[2];              \
            _Pragma("unroll")                                                   \
            for (int i_ = 0; i_ < 2; ++i_)                                      \
                af_[i_] = *(const short8*)&As[BR][(we * 32 + i_ * 16 + l16) * SP + kk_ * 32 + quad * 8]; \
            _Pragma("unroll")                                                   \
            for (int j_ = 0; j_ < 2; ++j_)                                      \
                bf_[j_] = *(const short8*)&Bs[BR][(wn * 32 + j_ * 16 + l16) * SP + kk_ * 32 + quad * 8]; \
            __builtin_amdgcn_s_setprio(1);                                      \
            _Pragma("unroll")                                                   \
            for (int i_ = 0; i_ < 2; ++i_)                                      \
                _Pragma("unroll")                                               \
                for (int j_ = 0; j_ < 2; ++j_)                                  \
                    acc[i_][j_] = __builtin_amdgcn_mfma_f32_16x16x32_bf16(af_[i_], bf_[j_], acc[i_][j_], 0, 0, 0); \
            __builtin_amdgcn_s_setprio(0); } } while (0)

#define SITER(t, VM, BW, WW, XX, BR) do {                                       \
        asm volatile("s_waitcnt vmcnt(" #VM ")" ::: "memory");                  \
        asm volatile("s_waitcnt lgkmcnt(0)" ::: "memory");                      \
        __builtin_amdgcn_s_barrier();                                           \
        asm volatile("" ::: "memory");                                          \
        SWRITE(BW, WW, XX);                                                     \
        if ((t) + 3 < 4) SGLOAD(WW, XX, (t) + 3);                               \
        SCOMP(BR); } while (0)

    f32x4 acc[2][2] = {};
    SGLOAD(Wa0, Xv0, 0);
    SGLOAD(Wa1, Xv1, 1);
    asm volatile("s_waitcnt vmcnt(6)" ::: "memory");
    SWRITE(0, Wa0, Xv0);
    SGLOAD(Wa0, Xv0, 2);
    SITER(0, 6, 1, Wa1, Xv1, 0);
    SITER(1, 6, 0, Wa0, Xv0, 1);
    SITER(2, 0, 1, Wa1, Xv1, 0);
    // final stage 3: no write, no load
    asm volatile("s_waitcnt lgkmcnt(0)" ::: "memory");
    __builtin_amdgcn_s_barrier();
    asm volatile("" ::: "memory");
    SCOMP(1);
#undef SGLOAD
#undef SWRITE
#undef SCOMP
#undef SITER

    // epilogue: bias + bf16 via LDS bounce, dense 128B row stores.
    __syncthreads();
    short* E = &As[0][0];   // 64 x EPS shorts = 9216 B, fits
    #pragma unroll
    for (int i = 0; i < 2; ++i)
        #pragma unroll
        for (int reg = 0; reg < 4; ++reg) {
            int e_l = we * 32 + i * 16 + quad * 4 + reg;
            float bv = bias[r * Dd + e0 + e_l];
            #pragma unroll
            for (int j = 0; j < 2; ++j)
                E[e_l * EPS + wn * 32 + j * 16 + l16] = f2bf(acc[i][j][reg] + bv);
        }
    __syncthreads();
    #pragma unroll
    for (int p = 0; p < 2; ++p) {
        int idx = tid + p * 256;
        int row = idx >> 3, c = idx & 7;
        *(short8*)(sup + (((size_t)((b * Rr + r) * Dd + e0 + row)) << 10) + n0 + c * 8) =
            *(const short8*)&E[row * EPS + c * 8];
    }
}

// ---------------- Stage 2: out = relu(sum_r adj @ sup^T), r fused into K ----------------
// 64m x 64e tile, K=8192 in 128 stages of 64 (stage t: r=t>>4, n0=(t&15)*64).
// Swizzle: L=(d&7)*64+(d>>3): XCD k owns mrows [16k,16k+16) of batch k>>1.
__global__ __launch_bounds__(256, 3) void gcn_gemm_kernel(
        const float* __restrict__ adj, const short* __restrict__ sup,
        float* __restrict__ out) {
    __shared__ short As[2][64 * SP];   // adj rows [m][k] (cvt bf16)
    __shared__ short Bs[2][64 * SP];   // sup rows [e][k]

    const int tid = threadIdx.x;
    const int wave = tid >> 6, lane = tid & 63;
    const int quad = lane >> 4, l16 = lane & 15;
    const int lrow = tid >> 3, lc = tid & 7;
    const int d = blockIdx.x;                 // 512
    const int L = (d & 7) * 64 + (d >> 3);    // bijective
    const int e_t = L & 3, mrow = L >> 2;     // mrow 0..127
    const int b = mrow >> 4;
    const int m0 = (mrow & 15) * 64, e0 = e_t * 64;
    const int wm = wave & 1, we = wave >> 1;

    f32x4  Aa0[4], Aa1[4];
    short8 Sv0[2], Sv1[2];

#define GGLOAD(AA, SS, t) do { int r_ = (t) >> 4, n0_ = ((t) & 15) * 64;        \
        const float* ap_ = adj + ((size_t)((b * Rr + r_) * Nn + m0)) * Nn + n0_; \
        const short* sp_ = sup + (((size_t)((b * Rr + r_) * Dd + e0)) << 10) + n0_; \
        _Pragma("unroll")                                                       \
        for (int p_ = 0; p_ < 2; ++p_) { int row_ = lrow + p_ * 32;             \
            const float* pa_ = ap_ + (size_t)row_ * Nn + lc * 8;                \
            AA[2 * p_]     = *(const f32x4*)pa_;                                \
            AA[2 * p_ + 1] = *(const f32x4*)(pa_ + 4);                          \
            SS[p_] = *(const short8*)(sp_ + ((size_t)row_ << 10) + lc * 8); } } while (0)

#define GWRITE(BW, AA, SS) do {                                                 \
        _Pragma("unroll")                                                       \
        for (int p_ = 0; p_ < 2; ++p_) { int row_ = lrow + p_ * 32;             \
            *(short8*)&As[BW][row_ * SP + lc * 8] = cvt8(AA[2 * p_], AA[2 * p_ + 1]); \
            *(short8*)&Bs[BW][row_ * SP + lc * 8] = SS[p_]; } } while (0)

#define GCOMP(BR) do {                                                          \
        _Pragma("unroll")                                                       \
        for (int kk_ = 0; kk_ < 2; ++kk_) { short8 af_[2], bf_[2];              \
            _Pragma("unroll")                                                   \
            for (int i_ = 0; i_ < 2; ++i_)                                      \
                af_[i_] = *(const short8*)&As[BR][(wm * 32 + i_ * 16 + l16) * SP + kk_ * 32 + quad * 8]; \
            _Pragma("unroll")                                                   \
            for (int j_ = 0; j_ < 2; ++j_)                                      \
                bf_[j_] = *(const short8*)&Bs[BR][(we * 32 + j_ * 16 + l16) * SP + kk_ * 32 + quad * 8]; \
            __builtin_amdgcn_s_setprio(1);                                      \
            _Pragma("unroll")                                                   \
            for (int i_ = 0; i_ < 2; ++i_)                                      \
                _Pragma("unroll")                                               \
                for (int j_ = 0; j_ < 2; ++j_)                                  \
                    acc[i_][j_] = __builtin_amdgcn_mfma_f32_16x16x32_bf16(af_[i_], bf_[j_], acc[i_][j_], 0, 0, 0); \
            __builtin_amdgcn_s_setprio(0); } } while (0)

#define GITER(t, VM, BW, AA, SS, BR) do {                                       \
        asm volatile("s_waitcnt vmcnt(" #VM ")" ::: "memory");                  \
        asm volatile("s_waitcnt lgkmcnt(0)" ::: "memory");                      \
        __builtin_amdgcn_s_barrier();                                           \
        asm volatile("" ::: "memory");                                          \
        GWRITE(BW, AA, SS);                                                     \
        if ((t) + 3 < 128) GGLOAD(AA, SS, (t) + 3);                             \
        GCOMP(BR); } while (0)

    f32x4 acc[2][2] = {};
    GGLOAD(Aa0, Sv0, 0);
    GGLOAD(Aa1, Sv1, 1);
    asm volatile("s_waitcnt vmcnt(6)" ::: "memory");
    GWRITE(0, Aa0, Sv0);
    GGLOAD(Aa0, Sv0, 2);
    for (int t = 0; t < 126; t += 2) {
        GITER(t,     6, 1, Aa1, Sv1, 0);
        GITER(t + 1, 6, 0, Aa0, Sv0, 1);
    }
    GITER(126, 0, 1, Aa1, Sv1, 0);
    // final stage 127: no write, no load
    asm volatile("s_waitcnt lgkmcnt(0)" ::: "memory");
    __builtin_amdgcn_s_barrier();
    asm volatile("" ::: "memory");
    GCOMP(1);
#undef GGLOAD
#undef GWRITE
#undef GCOMP
#undef GITER

    // epilogue: ReLU via f32 LDS bounce (spans As[0..1], 17.4KB), dense 256B row stores.
    __syncthreads();
    float* E = (float*)&As[0][0];
    #pragma unroll
    for (int i = 0; i < 2; ++i)
        #pragma unroll
        for (int reg = 0; reg < 4; ++reg) {
            int m_l = wm * 32 + i * 16 + quad * 4 + reg;
            #pragma unroll
            for (int j = 0; j < 2; ++j)
                E[m_l * EPF + we * 32 + j * 16 + l16] = fmaxf(acc[i][j][reg], 0.f);
        }
    __syncthreads();
    #pragma unroll
    for (int p = 0; p < 4; ++p) {
        int idx = tid + p * 256;
        int row = idx >> 4, c = idx & 15;
        *(f32x4*)(out + ((size_t)(b * Nn + m0 + row)) * Dd + e0 + c * 4) =
            *(const f32x4*)&E[row * EPF + c * 4];
    }
}

extern "C" void kernel_launch(void* const* d_in, const int* in_sizes, int n_in,
                              void* d_out, int out_size, void* d_ws, size_t ws_size,
                              hipStream_t stream) {
    const float* x    = (const float*)d_in[0];
    const float* adj  = (const float*)d_in[1];
    const float* W    = (const float*)d_in[2];
    const float* bias = (const float*)d_in[3];
    float* out = (float*)d_out;
    short* sup = (short*)d_ws;                          // ws[0:32MB)
    short* Wt  = (short*)((char*)d_ws + (32u << 20));   // ws[32MB:36MB)

    prep_w_kernel<<<dim3(4, 4, 8), 256, 0, stream>>>(W, Wt);
    support_kernel<<<4096, 256, 0, stream>>>(x, Wt, bias, sup);
    gcn_gemm_kernel<<<512, 256, 0, stream>>>(adj, sup, out);
}